// Round 3
// baseline (148.145 us; speedup 1.0000x reference)
//
#include <hip/hip_runtime.h>
#include <cstddef>

using bf16x8  = __attribute__((ext_vector_type(8))) short;
using f32x4   = __attribute__((ext_vector_type(4))) float;
using ushort8 = __attribute__((ext_vector_type(8))) unsigned short;

#define GLL16(gp, lp) __builtin_amdgcn_global_load_lds( \
    (const __attribute__((address_space(1))) unsigned int*)(const void*)(gp), \
    (__attribute__((address_space(3))) unsigned int*)(void*)(lp), 16, 0, 0)

__device__ __forceinline__ float exp2_f(float x){ float r; asm("v_exp_f32 %0, %1" : "=v"(r) : "v"(x)); return r; }
__device__ __forceinline__ float rcp_f (float x){ float r; asm("v_rcp_f32 %0, %1" : "=v"(r) : "v"(x)); return r; }

__device__ __forceinline__ unsigned short f2bf(float f){
  unsigned int u = __float_as_uint(f);
  u = u + 0x7FFFu + ((u >> 16) & 1u);
  return (unsigned short)(u >> 16);
}

// problem sizes: B=8 Q=16 KV=2048 NQ=NK=NV=H=512
#define KEYS_N   8388608
#define QUERY_N  65536
#define SCALE_2LOG2E 2.885390081777927f   // 2*log2(e): exp2(x*S) = exp(2x)

// workspace layout (bytes); total = 40,239,104
#define OFF_KEYS_BF   0u          // 16384x512 bf16
#define OFF_QUERY_BF  16777216u   // 128x512 bf16
#define OFF_WK_BF     16908288u   // 512x512 bf16
#define OFF_WQ_BF     17432576u   // 512x512 bf16
#define OFF_EQB       17956864u   // 128x512 f32: exp2(S*q_part)
#define OFF_EPART     18219008u   // 4 x [8*2048*16] f32 partial logits
#define OFF_SC        22413312u   // 8x2048x16 f32 scores
#define OFF_PART      23461888u   // 8x64x16x512 f32 partial outputs

// ---------------- K1: f32 -> bf16 conversion (keys, query, W split) -------
__global__ __launch_bounds__(256) void k_convert(
    const float* __restrict__ query, const float* __restrict__ keys,
    const float* __restrict__ W,
    unsigned short* __restrict__ keys_bf, unsigned short* __restrict__ query_bf,
    unsigned short* __restrict__ wk_bf, unsigned short* __restrict__ wq_bf)
{
  int idx = (blockIdx.x * 256 + threadIdx.x) * 8;
  const float* src;
  unsigned short* dst;
  if (idx < KEYS_N) { src = keys + idx; dst = keys_bf + idx; }
  else if (idx < KEYS_N + QUERY_N) { int e = idx - KEYS_N; src = query + e; dst = query_bf + e; }
  else {
    int e = idx - (KEYS_N + QUERY_N);
    int h = e >> 10, c = e & 1023;             // W row-major [512][1024]
    src = W + e;
    dst = (c < 512) ? (wq_bf + h * 512 + c) : (wk_bf + h * 512 + (c - 512));
  }
  float4 a = *(const float4*)src;
  float4 b = *(const float4*)(src + 4);
  ushort8 o;
  o[0]=f2bf(a.x); o[1]=f2bf(a.y); o[2]=f2bf(a.z); o[3]=f2bf(a.w);
  o[4]=f2bf(b.x); o[5]=f2bf(b.y); o[6]=f2bf(b.z); o[7]=f2bf(b.w);
  *(ushort8*)dst = o;
}

// ---------------- K2: small q-GEMM: eqb = exp2(S * query·Wq^T) ------------
// M=128 (all b,q rows), K=512, grid (4,1) over n-chunks of 128.
__global__ __launch_bounds__(256) void k_qgemm(
    const unsigned short* __restrict__ query_bf, const unsigned short* __restrict__ wq_bf,
    float* __restrict__ eqb)
{
  __shared__ short As[2][8192];
  __shared__ short Bs[2][8192];
  const int tid = threadIdx.x;
  const int l = tid & 63, w = tid >> 6;
  const int n0 = blockIdx.x * 128;
  const unsigned short* Bptr = wq_bf + (size_t)n0 * 512;
  const int eo_base = w * 2048 + l * 8;

  f32x4 acc[4][4];
  #pragma unroll
  for (int i = 0; i < 4; ++i)
    #pragma unroll
    for (int j = 0; j < 4; ++j) acc[i][j] = (f32x4){0.f,0.f,0.f,0.f};

  auto stage = [&](int buf, int kt) {
    const int k0 = kt * 64;
    #pragma unroll
    for (int r = 0; r < 4; ++r) {
      const int eo = eo_base + r * 512;
      const int row = eo >> 6, col = eo & 63;
      GLL16(query_bf + row * 512 + k0 + col, &As[buf][w * 2048 + r * 512]);
      GLL16(Bptr + row * 512 + k0 + col, &Bs[buf][w * 2048 + r * 512]);
    }
  };
  const int wm = w >> 1, wn = w & 1;
  const int fr = l & 15, fg = l >> 4;
  auto compute = [&](int buf) {
    #pragma unroll
    for (int ks = 0; ks < 2; ++ks) {
      bf16x8 af[4], bfv[4];
      #pragma unroll
      for (int i = 0; i < 4; ++i) {
        af[i]  = *(const bf16x8*)&As[buf][(wm*64 + i*16 + fr) * 64 + ks*32 + fg*8];
        bfv[i] = *(const bf16x8*)&Bs[buf][(wn*64 + i*16 + fr) * 64 + ks*32 + fg*8];
      }
      #pragma unroll
      for (int i = 0; i < 4; ++i)
        #pragma unroll
        for (int j = 0; j < 4; ++j)
          acc[i][j] = __builtin_amdgcn_mfma_f32_16x16x32_bf16(af[i], bfv[j], acc[i][j], 0, 0, 0);
    }
  };
  stage(0, 0);
  for (int kt = 0; kt < 8; ++kt) {
    __syncthreads();
    if (kt < 7) stage((kt + 1) & 1, kt + 1);
    compute(kt & 1);
  }
  #pragma unroll
  for (int j = 0; j < 4; ++j) {
    const int gh = n0 + wn*64 + j*16 + fr;
    #pragma unroll
    for (int i = 0; i < 4; ++i)
      #pragma unroll
      for (int r = 0; r < 4; ++r) {
        const int gm = wm*64 + i*16 + fg*4 + r;
        eqb[gm * 512 + gh] = exp2_f(acc[i][j][r] * SCALE_2LOG2E);
      }
  }
}

// ---------------- K3: FUSED k-GEMM + energy -------------------------------
// block (hc, by): GEMM 128x128 -> ek = exp2(S*(k_part+bias)) in LDS,
// then e_part[hc][r0][q] = -2 * sum_{h in chunk} v_h / (1 + ek*eq).
struct FusedSM {
  union {
    struct { short A[2][8192]; short B[2][8192]; } g;
    float ek[128 * 132];                    // stride 132: pad kills conflicts
  } u;
  float eqs[16 * 128];
};

__global__ __launch_bounds__(256, 2) void k_fused(
    const unsigned short* __restrict__ keys_bf, const unsigned short* __restrict__ wk_bf,
    const float* __restrict__ w_bias, const float* __restrict__ eqb,
    const float* __restrict__ vw, float* __restrict__ e_part)
{
  __shared__ FusedSM sm;
  const int tid = threadIdx.x;
  const int l = tid & 63, w = tid >> 6;
  const int hc = blockIdx.x;              // 0..3 h-chunk (= n-tile)
  const int by = blockIdx.y;              // 0..127 m-tile (128 k-rows)
  const int h0 = hc * 128;
  const int b  = by >> 4;                 // 16 m-tiles per batch

  const unsigned short* Aptr = keys_bf + (size_t)by * 128 * 512;
  const unsigned short* Bptr = wk_bf + (size_t)h0 * 512;
  const int eo_base = w * 2048 + l * 8;

  f32x4 acc[4][4];
  #pragma unroll
  for (int i = 0; i < 4; ++i)
    #pragma unroll
    for (int j = 0; j < 4; ++j) acc[i][j] = (f32x4){0.f,0.f,0.f,0.f};

  auto stage = [&](int buf, int kt) {
    const int k0 = kt * 64;
    #pragma unroll
    for (int r = 0; r < 4; ++r) {
      const int eo = eo_base + r * 512;
      const int row = eo >> 6, col = eo & 63;
      GLL16(Aptr + row * 512 + k0 + col, &sm.u.g.A[buf][w * 2048 + r * 512]);
      GLL16(Bptr + row * 512 + k0 + col, &sm.u.g.B[buf][w * 2048 + r * 512]);
    }
  };
  const int wm = w >> 1, wn = w & 1;
  const int fr = l & 15, fg = l >> 4;
  auto compute = [&](int buf) {
    #pragma unroll
    for (int ks = 0; ks < 2; ++ks) {
      bf16x8 af[4], bfv[4];
      #pragma unroll
      for (int i = 0; i < 4; ++i) {
        af[i]  = *(const bf16x8*)&sm.u.g.A[buf][(wm*64 + i*16 + fr) * 64 + ks*32 + fg*8];
        bfv[i] = *(const bf16x8*)&sm.u.g.B[buf][(wn*64 + i*16 + fr) * 64 + ks*32 + fg*8];
      }
      #pragma unroll
      for (int i = 0; i < 4; ++i)
        #pragma unroll
        for (int j = 0; j < 4; ++j)
          acc[i][j] = __builtin_amdgcn_mfma_f32_16x16x32_bf16(af[i], bfv[j], acc[i][j], 0, 0, 0);
    }
  };
  stage(0, 0);
  for (int kt = 0; kt < 8; ++kt) {
    __syncthreads();
    if (kt < 7) stage((kt + 1) & 1, kt + 1);
    compute(kt & 1);
  }
  __syncthreads();                         // all ds_reads done before overwrite

  // ek -> LDS (local h index 0..127); C/D layout: row=fg*4+r, col=fr
  #pragma unroll
  for (int j = 0; j < 4; ++j) {
    const int lc = wn*64 + j*16 + fr;
    const float bias = w_bias[h0 + lc];
    #pragma unroll
    for (int i = 0; i < 4; ++i)
      #pragma unroll
      for (int r = 0; r < 4; ++r) {
        const int lm = wm*64 + i*16 + fg*4 + r;
        sm.u.ek[lm * 132 + lc] = exp2_f((acc[i][j][r] + bias) * SCALE_2LOG2E);
      }
  }
  // stage eq chunk [16 q][128 h] (separate LDS region, no race with ek)
  {
    const int q = tid >> 4, c0 = (tid & 15) * 8;
    const float* src = eqb + (size_t)(b * 16 + q) * 512 + h0 + c0;
    *(float4*)&sm.eqs[q * 128 + c0]     = *(const float4*)src;
    *(float4*)&sm.eqs[q * 128 + c0 + 4] = *(const float4*)(src + 4);
  }
  // v weights (scaled by -2), lane owns h-cols {s*32+g*4+t, s*32+16+g*4+t}
  const int g = l & 3, kl = l >> 2;
  float vv[32];
  #pragma unroll
  for (int s = 0; s < 4; ++s) {
    const float4 a0 = *(const float4*)(vw + h0 + s*32 + g*4);
    const float4 a1 = *(const float4*)(vw + h0 + s*32 + 16 + g*4);
    vv[s*8+0]=-2.f*a0.x; vv[s*8+1]=-2.f*a0.y; vv[s*8+2]=-2.f*a0.z; vv[s*8+3]=-2.f*a0.w;
    vv[s*8+4]=-2.f*a1.x; vv[s*8+5]=-2.f*a1.y; vv[s*8+6]=-2.f*a1.z; vv[s*8+7]=-2.f*a1.w;
  }
  __syncthreads();

  // energy: wave w handles rows w*32..w*32+31 in 2 passes of 16
  #pragma unroll
  for (int p = 0; p < 2; ++p) {
    const int lr = w * 32 + p * 16 + kl;          // local k-row
    float ek[32];
    #pragma unroll
    for (int s = 0; s < 4; ++s) {
      *(float4*)&ek[s*8]     = *(const float4*)&sm.u.ek[lr*132 + s*32 + g*4];
      *(float4*)&ek[s*8 + 4] = *(const float4*)&sm.u.ek[lr*132 + s*32 + 16 + g*4];
    }
    const size_t epbase = (size_t)hc * 262144 + ((size_t)(by * 128 + lr)) * 16;
    #pragma unroll 2
    for (int q = 0; q < 16; ++q) {
      float a0 = 0.f, a1 = 0.f;
      #pragma unroll
      for (int s = 0; s < 4; ++s) {
        const float* er = &sm.eqs[q * 128 + s * 32 + g * 4];
        const float4 E0 = *(const float4*)er;
        const float4 E1 = *(const float4*)(er + 16);
        a0 = fmaf(vv[s*8+0], rcp_f(fmaf(ek[s*8+0], E0.x, 1.f)), a0);
        a1 = fmaf(vv[s*8+1], rcp_f(fmaf(ek[s*8+1], E0.y, 1.f)), a1);
        a0 = fmaf(vv[s*8+2], rcp_f(fmaf(ek[s*8+2], E0.z, 1.f)), a0);
        a1 = fmaf(vv[s*8+3], rcp_f(fmaf(ek[s*8+3], E0.w, 1.f)), a1);
        a0 = fmaf(vv[s*8+4], rcp_f(fmaf(ek[s*8+4], E1.x, 1.f)), a0);
        a1 = fmaf(vv[s*8+5], rcp_f(fmaf(ek[s*8+5], E1.y, 1.f)), a1);
        a0 = fmaf(vv[s*8+6], rcp_f(fmaf(ek[s*8+6], E1.z, 1.f)), a0);
        a1 = fmaf(vv[s*8+7], rcp_f(fmaf(ek[s*8+7], E1.w, 1.f)), a1);
      }
      float a = a0 + a1;
      a += __shfl_xor(a, 1, 64);
      a += __shfl_xor(a, 2, 64);
      if (g == 0) e_part[epbase + q] = a;
    }
  }
}

// ---------------- K4: softmax over k: sum 4 partials, normalize -----------
__global__ __launch_bounds__(256) void k_softmax(
    const float* __restrict__ e_part, float* __restrict__ sc)
{
  const int b = blockIdx.x >> 4, q = blockIdx.x & 15;
  const int base = b * 32768 + q;           // stride 16 over k
  const int tid = threadIdx.x;
  __shared__ float redm[4], reds[4];

  float vals[8];
  float mx = -1e30f;
  #pragma unroll
  for (int i = 0; i < 8; ++i) {
    const int x = base + (tid + i * 256) * 16;
    vals[i] = (e_part[x] + e_part[x + 262144]) + (e_part[x + 524288] + e_part[x + 786432]);
    mx = fmaxf(mx, vals[i]);
  }
  #pragma unroll
  for (int msk = 1; msk < 64; msk <<= 1) mx = fmaxf(mx, __shfl_xor(mx, msk, 64));
  if ((tid & 63) == 0) redm[tid >> 6] = mx;
  __syncthreads();
  mx = fmaxf(fmaxf(redm[0], redm[1]), fmaxf(redm[2], redm[3]));

  float ex[8], sum = 0.f;
  #pragma unroll
  for (int i = 0; i < 8; ++i) { ex[i] = __expf(vals[i] - mx); sum += ex[i]; }
  #pragma unroll
  for (int msk = 1; msk < 64; msk <<= 1) sum += __shfl_xor(sum, msk, 64);
  if ((tid & 63) == 0) reds[tid >> 6] = sum;
  __syncthreads();
  sum = reds[0] + reds[1] + reds[2] + reds[3];
  const float r = 1.f / sum;
  #pragma unroll
  for (int i = 0; i < 8; ++i) sc[base + (tid + i * 256) * 16] = ex[i] * r;
}

// ---------------- K5: partial PV (64 chunks of 32 k) ----------------------
__global__ __launch_bounds__(256) void k_pv(
    const float* __restrict__ values, const float* __restrict__ sc,
    float* __restrict__ part)
{
  __shared__ float s_sc[64 * 16];
  const int c = blockIdx.x, b = blockIdx.y;   // c: 32 blocks of 64 k
  const int tid = threadIdx.x;
  const float* ssrc = sc + (b * 2048 + c * 64) * 16;
  *(float4*)&s_sc[tid * 4] = *(const float4*)&ssrc[tid * 4];
  __syncthreads();

  const int kg = tid >> 7, nt = tid & 127;    // 2 k-groups x 128 n-slots
  float4 acc[16];
  #pragma unroll
  for (int q = 0; q < 16; ++q) acc[q] = make_float4(0.f, 0.f, 0.f, 0.f);

  const float* vbase = values + ((size_t)(b * 2048 + c * 64 + kg * 32)) * 512 + nt * 4;
  #pragma unroll 2
  for (int kk = 0; kk < 32; ++kk) {
    const float4 v4 = *(const float4*)(vbase + (size_t)kk * 512);
    const int ks = (kg * 32 + kk) * 16;
    #pragma unroll
    for (int g = 0; g < 4; ++g) {
      const float4 s4 = *(const float4*)&s_sc[ks + g * 4];
      #define PV_ACC(qi, sv) { float4& a = acc[qi]; a.x += v4.x*(sv); a.y += v4.y*(sv); a.z += v4.z*(sv); a.w += v4.w*(sv); }
      PV_ACC(g*4+0, s4.x); PV_ACC(g*4+1, s4.y); PV_ACC(g*4+2, s4.z); PV_ACC(g*4+3, s4.w);
      #undef PV_ACC
    }
  }
  const int cc = c * 2 + kg;                  // 64 chunks
  float* pbase = part + ((size_t)((b * 64 + cc) * 16)) * 512 + nt * 4;
  #pragma unroll
  for (int q = 0; q < 16; ++q) *(float4*)(pbase + q * 512) = acc[q];
}

// ---------------- K6: reduce 64 chunks -> out[b,q,n] ----------------------
__global__ __launch_bounds__(256) void k_reduce(
    const float* __restrict__ part, float* __restrict__ out)
{
  const int o = blockIdx.x * 256 + threadIdx.x;   // < 65536
  const int n = o & 511;
  const int q = (o >> 9) & 15;
  const int b = o >> 13;
  const float* p = part + ((size_t)(b * 64 * 16 + q)) * 512 + n;
  float s = 0.f;
  #pragma unroll
  for (int cc = 0; cc < 64; ++cc) s += p[(size_t)cc * 16 * 512];
  out[o] = s;
}

extern "C" void kernel_launch(void* const* d_in, const int* in_sizes, int n_in,
                              void* d_out, int out_size, void* d_ws, size_t ws_size,
                              hipStream_t stream)
{
  const float* query  = (const float*)d_in[0];
  const float* keys   = (const float*)d_in[1];
  const float* values = (const float*)d_in[2];
  const float* W      = (const float*)d_in[3];
  const float* w_bias = (const float*)d_in[4];
  const float* vw     = (const float*)d_in[5];
  // d_in[6] (v_bias) + sum_h v_h are (k)-constant logit shifts -> softmax-invariant.

  char* ws = (char*)d_ws;
  unsigned short* keys_bf  = (unsigned short*)(ws + OFF_KEYS_BF);
  unsigned short* query_bf = (unsigned short*)(ws + OFF_QUERY_BF);
  unsigned short* wk_bf    = (unsigned short*)(ws + OFF_WK_BF);
  unsigned short* wq_bf    = (unsigned short*)(ws + OFF_WQ_BF);
  float* eqb    = (float*)(ws + OFF_EQB);
  float* e_part = (float*)(ws + OFF_EPART);
  float* sc     = (float*)(ws + OFF_SC);
  float* part   = (float*)(ws + OFF_PART);

  hipLaunchKernelGGL(k_convert, dim3(4384), dim3(256), 0, stream,
                     query, keys, W, keys_bf, query_bf, wk_bf, wq_bf);
  hipLaunchKernelGGL(k_qgemm, dim3(4), dim3(256), 0, stream, query_bf, wq_bf, eqb);
  hipLaunchKernelGGL(k_fused, dim3(4, 128), dim3(256), 0, stream,
                     keys_bf, wk_bf, w_bias, eqb, vw, e_part);
  hipLaunchKernelGGL(k_softmax, dim3(128), dim3(256), 0, stream, e_part, sc);
  hipLaunchKernelGGL(k_pv, dim3(32, 8), dim3(256), 0, stream, values, sc, part);
  hipLaunchKernelGGL(k_reduce, dim3(256), dim3(256), 0, stream, part, (float*)d_out);
}

// Round 4
// 105.066 us; speedup vs baseline: 1.4100x; 1.4100x over previous
//
#include <hip/hip_runtime.h>
#include <cstddef>

using bf16x8  = __attribute__((ext_vector_type(8))) short;
using f32x4   = __attribute__((ext_vector_type(4))) float;
using ushort8 = __attribute__((ext_vector_type(8))) unsigned short;

#define GLL16(gp, lp) __builtin_amdgcn_global_load_lds( \
    (const __attribute__((address_space(1))) unsigned int*)(const void*)(gp), \
    (__attribute__((address_space(3))) unsigned int*)(void*)(lp), 16, 0, 0)

__device__ __forceinline__ float exp2_f(float x){ float r; asm("v_exp_f32 %0, %1" : "=v"(r) : "v"(x)); return r; }
__device__ __forceinline__ float rcp_f (float x){ float r; asm("v_rcp_f32 %0, %1" : "=v"(r) : "v"(x)); return r; }

__device__ __forceinline__ unsigned short f2bf(float f){
  unsigned int u = __float_as_uint(f);
  u = u + 0x7FFFu + ((u >> 16) & 1u);
  return (unsigned short)(u >> 16);
}

// problem sizes: B=8 Q=16 KV=2048 NQ=NK=NV=H=512
#define KEYS_N   8388608
#define QUERY_N  65536
#define SCALE_2LOG2E 2.885390081777927f   // 2*log2(e): exp2(x*S) = exp(2x)
#define EKS 136                           // ek LDS row stride (words): 8-bank rotate/row

// workspace layout (bytes); total = 40,239,104
#define OFF_KEYS_BF   0u          // 16384x512 bf16
#define OFF_QUERY_BF  16777216u   // 128x512 bf16
#define OFF_WK_BF     16908288u   // 512x512 bf16
#define OFF_WQ_BF     17432576u   // 512x512 bf16
#define OFF_EQB       17956864u   // 128x512 f32: exp2(S*q_part)
#define OFF_EPART     18219008u   // 4 x [8*2048*16] f32 partial logits
#define OFF_SC        22413312u   // 8x2048x16 f32 scores
#define OFF_PART      23461888u   // 8x64x16x512 f32 partial outputs

// ---------------- K1: f32 -> bf16 conversion (keys, query, W split) -------
__global__ __launch_bounds__(256) void k_convert(
    const float* __restrict__ query, const float* __restrict__ keys,
    const float* __restrict__ W,
    unsigned short* __restrict__ keys_bf, unsigned short* __restrict__ query_bf,
    unsigned short* __restrict__ wk_bf, unsigned short* __restrict__ wq_bf)
{
  int idx = (blockIdx.x * 256 + threadIdx.x) * 8;
  const float* src;
  unsigned short* dst;
  if (idx < KEYS_N) { src = keys + idx; dst = keys_bf + idx; }
  else if (idx < KEYS_N + QUERY_N) { int e = idx - KEYS_N; src = query + e; dst = query_bf + e; }
  else {
    int e = idx - (KEYS_N + QUERY_N);
    int h = e >> 10, c = e & 1023;             // W row-major [512][1024]
    src = W + e;
    dst = (c < 512) ? (wq_bf + h * 512 + c) : (wk_bf + h * 512 + (c - 512));
  }
  float4 a = *(const float4*)src;
  float4 b = *(const float4*)(src + 4);
  ushort8 o;
  o[0]=f2bf(a.x); o[1]=f2bf(a.y); o[2]=f2bf(a.z); o[3]=f2bf(a.w);
  o[4]=f2bf(b.x); o[5]=f2bf(b.y); o[6]=f2bf(b.z); o[7]=f2bf(b.w);
  *(ushort8*)dst = o;
}

// Staging with XOR-swizzled GLOBAL source (LDS dest stays linear for gload_lds):
// LDS[row][c8] holds global chunk c8 ^ (row&7); read chunk c at c ^ (row&7).
// Quarter-wave fragment reads then hit all 8 bank-groups, 2 addrs each: conflict-free.

// ---------------- K2: small q-GEMM: eqb = exp2(S * query·Wq^T) ------------
__global__ __launch_bounds__(256) void k_qgemm(
    const unsigned short* __restrict__ query_bf, const unsigned short* __restrict__ wq_bf,
    float* __restrict__ eqb)
{
  __shared__ short As[2][8192];
  __shared__ short Bs[2][8192];
  const int tid = threadIdx.x;
  const int l = tid & 63, w = tid >> 6;
  const int n0 = blockIdx.x * 128;
  const unsigned short* Bptr = wq_bf + (size_t)n0 * 512;

  const int srow = w * 32 + (l >> 3);          // staging row (r adds 8)
  const int scol = ((l & 7) ^ (l >> 3)) * 8;   // swizzled 16B chunk

  f32x4 acc[4][4];
  #pragma unroll
  for (int i = 0; i < 4; ++i)
    #pragma unroll
    for (int j = 0; j < 4; ++j) acc[i][j] = (f32x4){0.f,0.f,0.f,0.f};

  auto stage = [&](int buf, int kt) {
    const int k0 = kt * 64;
    #pragma unroll
    for (int r = 0; r < 4; ++r) {
      GLL16(query_bf + (srow + r * 8) * 512 + k0 + scol, &As[buf][w * 2048 + r * 512]);
      GLL16(Bptr     + (srow + r * 8) * 512 + k0 + scol, &Bs[buf][w * 2048 + r * 512]);
    }
  };
  const int wm = w >> 1, wn = w & 1;
  const int fr = l & 15, fg = l >> 4;
  const int axk = fr & 7;                      // read-side XOR key
  auto compute = [&](int buf) {
    #pragma unroll
    for (int ks = 0; ks < 2; ++ks) {
      bf16x8 af[4], bfv[4];
      #pragma unroll
      for (int i = 0; i < 4; ++i) {
        af[i]  = *(const bf16x8*)&As[buf][(wm*64 + i*16 + fr) * 64 + ((ks*4 + fg) ^ axk) * 8];
        bfv[i] = *(const bf16x8*)&Bs[buf][(wn*64 + i*16 + fr) * 64 + ((ks*4 + fg) ^ axk) * 8];
      }
      #pragma unroll
      for (int i = 0; i < 4; ++i)
        #pragma unroll
        for (int j = 0; j < 4; ++j)
          acc[i][j] = __builtin_amdgcn_mfma_f32_16x16x32_bf16(af[i], bfv[j], acc[i][j], 0, 0, 0);
    }
  };
  stage(0, 0);
  for (int kt = 0; kt < 8; ++kt) {
    __syncthreads();
    if (kt < 7) stage((kt + 1) & 1, kt + 1);
    compute(kt & 1);
  }
  #pragma unroll
  for (int j = 0; j < 4; ++j) {
    const int gh = n0 + wn*64 + j*16 + fr;
    #pragma unroll
    for (int i = 0; i < 4; ++i)
      #pragma unroll
      for (int r = 0; r < 4; ++r) {
        const int gm = wm*64 + i*16 + fg*4 + r;
        eqb[gm * 512 + gh] = exp2_f(acc[i][j][r] * SCALE_2LOG2E);
      }
  }
}

// ---------------- K3: FUSED k-GEMM + energy -------------------------------
struct FusedSM {
  union {
    struct { short A[2][8192]; short B[2][8192]; } g;
    float ek[128 * EKS];
  } u;
  float eqs[16 * 128];
};

__global__ __launch_bounds__(256, 2) void k_fused(
    const unsigned short* __restrict__ keys_bf, const unsigned short* __restrict__ wk_bf,
    const float* __restrict__ w_bias, const float* __restrict__ eqb,
    const float* __restrict__ vw, float* __restrict__ e_part)
{
  __shared__ FusedSM sm;
  const int tid = threadIdx.x;
  const int l = tid & 63, w = tid >> 6;
  const int by = blockIdx.x;              // 0..127 m-tile (128 k-rows)
  const int hc = blockIdx.y;              // 0..3 h-chunk (= n-tile)
  const int h0 = hc * 128;
  const int b  = by >> 4;                 // 16 m-tiles per batch

  const unsigned short* Aptr = keys_bf + (size_t)by * 128 * 512;
  const unsigned short* Bptr = wk_bf + (size_t)h0 * 512;

  const int srow = w * 32 + (l >> 3);
  const int scol = ((l & 7) ^ (l >> 3)) * 8;

  f32x4 acc[4][4];
  #pragma unroll
  for (int i = 0; i < 4; ++i)
    #pragma unroll
    for (int j = 0; j < 4; ++j) acc[i][j] = (f32x4){0.f,0.f,0.f,0.f};

  auto stage = [&](int buf, int kt) {
    const int k0 = kt * 64;
    #pragma unroll
    for (int r = 0; r < 4; ++r) {
      GLL16(Aptr + (srow + r * 8) * 512 + k0 + scol, &sm.u.g.A[buf][w * 2048 + r * 512]);
      GLL16(Bptr + (srow + r * 8) * 512 + k0 + scol, &sm.u.g.B[buf][w * 2048 + r * 512]);
    }
  };
  const int wm = w >> 1, wn = w & 1;
  const int fr = l & 15, fg = l >> 4;
  const int axk = fr & 7;
  auto compute = [&](int buf) {
    #pragma unroll
    for (int ks = 0; ks < 2; ++ks) {
      bf16x8 af[4], bfv[4];
      #pragma unroll
      for (int i = 0; i < 4; ++i) {
        af[i]  = *(const bf16x8*)&sm.u.g.A[buf][(wm*64 + i*16 + fr) * 64 + ((ks*4 + fg) ^ axk) * 8];
        bfv[i] = *(const bf16x8*)&sm.u.g.B[buf][(wn*64 + i*16 + fr) * 64 + ((ks*4 + fg) ^ axk) * 8];
      }
      #pragma unroll
      for (int i = 0; i < 4; ++i)
        #pragma unroll
        for (int j = 0; j < 4; ++j)
          acc[i][j] = __builtin_amdgcn_mfma_f32_16x16x32_bf16(af[i], bfv[j], acc[i][j], 0, 0, 0);
    }
  };
  stage(0, 0);
  for (int kt = 0; kt < 8; ++kt) {
    __syncthreads();
    if (kt < 7) stage((kt + 1) & 1, kt + 1);
    compute(kt & 1);
  }
  __syncthreads();                         // all ds_reads done before overwrite

  // ek -> LDS; C/D layout: row=fg*4+r, col=fr
  #pragma unroll
  for (int j = 0; j < 4; ++j) {
    const int lc = wn*64 + j*16 + fr;
    const float bias = w_bias[h0 + lc];
    #pragma unroll
    for (int i = 0; i < 4; ++i)
      #pragma unroll
      for (int r = 0; r < 4; ++r) {
        const int lm = wm*64 + i*16 + fg*4 + r;
        sm.u.ek[lm * EKS + lc] = exp2_f((acc[i][j][r] + bias) * SCALE_2LOG2E);
      }
  }
  // stage eq chunk [16 q][128 h]
  {
    const int q = tid >> 4, c0 = (tid & 15) * 8;
    const float* src = eqb + (size_t)(b * 16 + q) * 512 + h0 + c0;
    *(float4*)&sm.eqs[q * 128 + c0]     = *(const float4*)src;
    *(float4*)&sm.eqs[q * 128 + c0 + 4] = *(const float4*)(src + 4);
  }
  // v weights (scaled by -2), lane owns h-cols {s*32+g*4+t, s*32+16+g*4+t}
  const int g = l & 3, kl = l >> 2;
  float vv[32];
  #pragma unroll
  for (int s = 0; s < 4; ++s) {
    const float4 a0 = *(const float4*)(vw + h0 + s*32 + g*4);
    const float4 a1 = *(const float4*)(vw + h0 + s*32 + 16 + g*4);
    vv[s*8+0]=-2.f*a0.x; vv[s*8+1]=-2.f*a0.y; vv[s*8+2]=-2.f*a0.z; vv[s*8+3]=-2.f*a0.w;
    vv[s*8+4]=-2.f*a1.x; vv[s*8+5]=-2.f*a1.y; vv[s*8+6]=-2.f*a1.z; vv[s*8+7]=-2.f*a1.w;
  }
  __syncthreads();

  // energy: wave w handles rows w*32..w*32+31 in 2 passes of 16
  #pragma unroll
  for (int p = 0; p < 2; ++p) {
    const int lr = w * 32 + p * 16 + kl;          // local k-row
    float ek[32];
    #pragma unroll
    for (int s = 0; s < 4; ++s) {
      *(float4*)&ek[s*8]     = *(const float4*)&sm.u.ek[lr*EKS + s*32 + g*4];
      *(float4*)&ek[s*8 + 4] = *(const float4*)&sm.u.ek[lr*EKS + s*32 + 16 + g*4];
    }
    const size_t epbase = (size_t)hc * 262144 + ((size_t)(by * 128 + lr)) * 16;
    #pragma unroll 2
    for (int q = 0; q < 16; ++q) {
      float a0 = 0.f, a1 = 0.f;
      #pragma unroll
      for (int s = 0; s < 4; ++s) {
        const float* er = &sm.eqs[q * 128 + s * 32 + g * 4];
        const float4 E0 = *(const float4*)er;
        const float4 E1 = *(const float4*)(er + 16);
        a0 = fmaf(vv[s*8+0], rcp_f(fmaf(ek[s*8+0], E0.x, 1.f)), a0);
        a1 = fmaf(vv[s*8+1], rcp_f(fmaf(ek[s*8+1], E0.y, 1.f)), a1);
        a0 = fmaf(vv[s*8+2], rcp_f(fmaf(ek[s*8+2], E0.z, 1.f)), a0);
        a1 = fmaf(vv[s*8+3], rcp_f(fmaf(ek[s*8+3], E0.w, 1.f)), a1);
        a0 = fmaf(vv[s*8+4], rcp_f(fmaf(ek[s*8+4], E1.x, 1.f)), a0);
        a1 = fmaf(vv[s*8+5], rcp_f(fmaf(ek[s*8+5], E1.y, 1.f)), a1);
        a0 = fmaf(vv[s*8+6], rcp_f(fmaf(ek[s*8+6], E1.z, 1.f)), a0);
        a1 = fmaf(vv[s*8+7], rcp_f(fmaf(ek[s*8+7], E1.w, 1.f)), a1);
      }
      float a = a0 + a1;
      a += __shfl_xor(a, 1, 64);
      a += __shfl_xor(a, 2, 64);
      if (g == 0) e_part[epbase + q] = a;
    }
  }
}

// ---------------- K4: softmax over k: sum 4 partials, normalize -----------
__global__ __launch_bounds__(256) void k_softmax(
    const float* __restrict__ e_part, float* __restrict__ sc)
{
  const int b = blockIdx.x >> 4, q = blockIdx.x & 15;
  const int base = b * 32768 + q;           // stride 16 over k
  const int tid = threadIdx.x;
  __shared__ float redm[4], reds[4];

  float vals[8];
  float mx = -1e30f;
  #pragma unroll
  for (int i = 0; i < 8; ++i) {
    const int x = base + (tid + i * 256) * 16;
    vals[i] = (e_part[x] + e_part[x + 262144]) + (e_part[x + 524288] + e_part[x + 786432]);
    mx = fmaxf(mx, vals[i]);
  }
  #pragma unroll
  for (int msk = 1; msk < 64; msk <<= 1) mx = fmaxf(mx, __shfl_xor(mx, msk, 64));
  if ((tid & 63) == 0) redm[tid >> 6] = mx;
  __syncthreads();
  mx = fmaxf(fmaxf(redm[0], redm[1]), fmaxf(redm[2], redm[3]));

  float ex[8], sum = 0.f;
  #pragma unroll
  for (int i = 0; i < 8; ++i) { ex[i] = __expf(vals[i] - mx); sum += ex[i]; }
  #pragma unroll
  for (int msk = 1; msk < 64; msk <<= 1) sum += __shfl_xor(sum, msk, 64);
  if ((tid & 63) == 0) reds[tid >> 6] = sum;
  __syncthreads();
  sum = reds[0] + reds[1] + reds[2] + reds[3];
  const float r = 1.f / sum;
  #pragma unroll
  for (int i = 0; i < 8; ++i) sc[base + (tid + i * 256) * 16] = ex[i] * r;
}

// ---------------- K5: partial PV (64 chunks of 32 k) ----------------------
__global__ __launch_bounds__(256) void k_pv(
    const float* __restrict__ values, const float* __restrict__ sc,
    float* __restrict__ part)
{
  __shared__ float s_sc[64 * 16];
  const int c = blockIdx.x, b = blockIdx.y;   // c: 32 blocks of 64 k
  const int tid = threadIdx.x;
  const float* ssrc = sc + (b * 2048 + c * 64) * 16;
  *(float4*)&s_sc[tid * 4] = *(const float4*)&ssrc[tid * 4];
  __syncthreads();

  const int kg = tid >> 7, nt = tid & 127;    // 2 k-groups x 128 n-slots
  float4 acc[16];
  #pragma unroll
  for (int q = 0; q < 16; ++q) acc[q] = make_float4(0.f, 0.f, 0.f, 0.f);

  const float* vbase = values + ((size_t)(b * 2048 + c * 64 + kg * 32)) * 512 + nt * 4;
  #pragma unroll 2
  for (int kk = 0; kk < 32; ++kk) {
    const float4 v4 = *(const float4*)(vbase + (size_t)kk * 512);
    const int ks = (kg * 32 + kk) * 16;
    #pragma unroll
    for (int g = 0; g < 4; ++g) {
      const float4 s4 = *(const float4*)&s_sc[ks + g * 4];
      #define PV_ACC(qi, sv) { float4& a = acc[qi]; a.x += v4.x*(sv); a.y += v4.y*(sv); a.z += v4.z*(sv); a.w += v4.w*(sv); }
      PV_ACC(g*4+0, s4.x); PV_ACC(g*4+1, s4.y); PV_ACC(g*4+2, s4.z); PV_ACC(g*4+3, s4.w);
      #undef PV_ACC
    }
  }
  const int cc = c * 2 + kg;                  // 64 chunks
  float* pbase = part + ((size_t)((b * 64 + cc) * 16)) * 512 + nt * 4;
  #pragma unroll
  for (int q = 0; q < 16; ++q) *(float4*)(pbase + q * 512) = acc[q];
}

// ---------------- K6: reduce 64 chunks -> out[b,q,n] ----------------------
__global__ __launch_bounds__(256) void k_reduce(
    const float* __restrict__ part, float* __restrict__ out)
{
  const int o = blockIdx.x * 256 + threadIdx.x;   // < 65536
  const int n = o & 511;
  const int q = (o >> 9) & 15;
  const int b = o >> 13;
  const float* p = part + ((size_t)(b * 64 * 16 + q)) * 512 + n;
  float s = 0.f;
  #pragma unroll
  for (int cc = 0; cc < 64; ++cc) s += p[(size_t)cc * 16 * 512];
  out[o] = s;
}

extern "C" void kernel_launch(void* const* d_in, const int* in_sizes, int n_in,
                              void* d_out, int out_size, void* d_ws, size_t ws_size,
                              hipStream_t stream)
{
  const float* query  = (const float*)d_in[0];
  const float* keys   = (const float*)d_in[1];
  const float* values = (const float*)d_in[2];
  const float* W      = (const float*)d_in[3];
  const float* w_bias = (const float*)d_in[4];
  const float* vw     = (const float*)d_in[5];
  // d_in[6] (v_bias) + sum_h v_h are (k)-constant logit shifts -> softmax-invariant.

  char* ws = (char*)d_ws;
  unsigned short* keys_bf  = (unsigned short*)(ws + OFF_KEYS_BF);
  unsigned short* query_bf = (unsigned short*)(ws + OFF_QUERY_BF);
  unsigned short* wk_bf    = (unsigned short*)(ws + OFF_WK_BF);
  unsigned short* wq_bf    = (unsigned short*)(ws + OFF_WQ_BF);
  float* eqb    = (float*)(ws + OFF_EQB);
  float* e_part = (float*)(ws + OFF_EPART);
  float* sc     = (float*)(ws + OFF_SC);
  float* part   = (float*)(ws + OFF_PART);

  hipLaunchKernelGGL(k_convert, dim3(4384), dim3(256), 0, stream,
                     query, keys, W, keys_bf, query_bf, wk_bf, wq_bf);
  hipLaunchKernelGGL(k_qgemm, dim3(4), dim3(256), 0, stream, query_bf, wq_bf, eqb);
  hipLaunchKernelGGL(k_fused, dim3(128, 4), dim3(256), 0, stream,
                     keys_bf, wk_bf, w_bias, eqb, vw, e_part);
  hipLaunchKernelGGL(k_softmax, dim3(128), dim3(256), 0, stream, e_part, sc);
  hipLaunchKernelGGL(k_pv, dim3(32, 8), dim3(256), 0, stream, values, sc, part);
  hipLaunchKernelGGL(k_reduce, dim3(256), dim3(256), 0, stream, part, (float*)d_out);
}